// Round 10
// baseline (2393.606 us; speedup 1.0000x reference)
//
#include <hip/hip_runtime.h>
#include <hip/hip_bf16.h>
#include <math.h>

// Problem constants (B,L,H,D fixed by setup_inputs; S == L)
#define B_   4
#define L_   2048
#define H_   8
#define D_   64
#define NTOP 38          // int(5*ln(2048)) = 38
#define SAMPK 38
#define NIDX (L_*SAMPK)  // 77824
#define HALFN (NIDX/2)   // 38912

// ===== RNG history =====
// r3-r6 tested JAX threefry WITHOUT the randint key-split -> all invalid tests
//   (jax._src.random._randint does `k1,k2 = _split(key)`; lower_bits from k2).
// r7-r9 numpy/torch hypotheses -> falsified (PCG64-64bit, MT 2w/elem, MT 1w/elem).
// THIS ROUND (10): JAX partitionable (default since jax 0.5) WITH split:
//   k2 = threefry((0,42), (0,1));  idx[t] = (y0^y1 @ (k2,(0,t))) & 2047.
// Fallback (11): JAX original stream WITH split:
//   k2 = (y1((0,42),(0,2)), y1((0,42),(1,3))); iota(77824) split-half under k2.
#define RNG_MODE 10

// ---------------- Threefry-2x32 (standard 20-round, KAT-verified) ----------------
__device__ __forceinline__ uint32_t rotl32(uint32_t v, int d) {
  return (v << d) | (v >> (32 - d));
}

__device__ __forceinline__ void threefry2x32(uint32_t k0, uint32_t k1,
                                             uint32_t x0, uint32_t x1,
                                             uint32_t& y0, uint32_t& y1) {
  const uint32_t ks2 = k0 ^ k1 ^ 0x1BD11BDAu;
  const uint32_t ks[3] = {k0, k1, ks2};
  x0 += k0; x1 += k1;
  const int ra[4] = {13, 15, 26, 6};
  const int rb[4] = {17, 29, 16, 24};
#pragma unroll
  for (int g = 0; g < 5; ++g) {
    const int* r = (g & 1) ? rb : ra;
#pragma unroll
    for (int i = 0; i < 4; ++i) {
      x0 += x1;
      x1 = rotl32(x1, r[i]);
      x1 ^= x0;
    }
    x0 += ks[(g + 1) % 3];
    x1 += ks[(g + 2) % 3] + (uint32_t)(g + 1);
  }
  y0 = x0; y1 = x1;
}

// Derive k2 = second key from _split(key(42)) per the active stream flavor.
__device__ __forceinline__ void derive_k2(uint32_t& k2_0, uint32_t& k2_1) {
#if RNG_MODE == 10
  // partitionable fold-like split: key_i = threefry(key, ctr=(0,i)); i=1
  threefry2x32(0u, 42u, 0u, 1u, k2_0, k2_1);
#else
  // original split: bits = threefry(key, iota(4)) with split-half pairing
  // pairs (0,2),(1,3); out=[y0(0,2), y0(1,3), y1(0,2), y1(1,3)]; k2=(out[2],out[3])
  uint32_t a0, a2, a1, a3;
  threefry2x32(0u, 42u, 0u, 2u, a0, a2);
  threefry2x32(0u, 42u, 1u, 3u, a1, a3);
  k2_0 = a2; k2_1 = a3;
#endif
}

// index_sample flat[t], t = q*SAMPK + j. span=2048 pow2 -> multiplier=0 ->
// idx = lower_bits % 2048, lower_bits drawn under k2.
__device__ __forceinline__ int sample_idx(int t, uint32_t k2_0, uint32_t k2_1) {
  uint32_t y0, y1;
#if RNG_MODE == 10
  threefry2x32(k2_0, k2_1, 0u, (uint32_t)t, y0, y1);
  return (int)((y0 ^ y1) & 2047u);
#else
  uint32_t x0, x1;
  if (t < HALFN) { x0 = (uint32_t)t;           x1 = (uint32_t)(t + HALFN); }
  else           { x0 = (uint32_t)(t - HALFN); x1 = (uint32_t)t; }
  threefry2x32(k2_0, k2_1, x0, x1, y0, y1);
  uint32_t bits = (t < HALFN) ? y0 : y1;
  return (int)(bits & 2047u);
#endif
}

// ---------------- cumsum(V) along L -> out (f32) ----------------
__global__ __launch_bounds__(1024) void cumsum_kernel(const float* __restrict__ V,
                                                      float* __restrict__ out) {
  int bh = blockIdx.x;
  int h = bh % H_, b = bh / H_;
  int tid = threadIdx.x;
  int d = tid & 63;
  int c = tid >> 6;               // 16 chunks of 128
  const int CHUNK = L_ / 16;      // 128
  __shared__ float cs[16][D_];
  size_t base = (((size_t)b * L_) * H_ + h) * D_ + d;
  const size_t lstride = (size_t)H_ * D_;   // 512
  float s = 0.f;
  for (int l = c * CHUNK; l < (c + 1) * CHUNK; ++l)
    s += V[base + (size_t)l * lstride];
  cs[c][d] = s;
  __syncthreads();
  float run = 0.f;
  for (int cc = 0; cc < c; ++cc) run += cs[cc][d];
  for (int l = c * CHUNK; l < (c + 1) * CHUNK; ++l) {
    run += V[base + (size_t)l * lstride];
    out[base + (size_t)l * lstride] = run;
  }
}

// ---------------- fused: M -> top-38 -> attention overwrite ----------------
// One block per (b,h). Zero global scratch (ws_size tiny -> never touch d_ws).
__global__ __launch_bounds__(256) void fused_kernel(const float* __restrict__ Q,
                                                    const float* __restrict__ K,
                                                    const float* __restrict__ V,
                                                    float* __restrict__ out) {
  int bh = blockIdx.x;            // b*H + h
  int h = bh % H_, b = bh / H_;
  int tid = threadIdx.x;

  __shared__ float sm[L_];        // M values; reused as score buffer in phase C
  __shared__ float redv[256];
  __shared__ int   redi[256];
  __shared__ int   mtop_s[NTOP];
  __shared__ float qs[D_];
  __shared__ float part[4][D_];

  uint32_t k2_0, k2_1;
  derive_k2(k2_0, k2_1);

  // ---- Phase A: M[q] = max_j(q.k_j) - sum_j(q.k_j)/S over 38 sampled keys ----
  for (int q = tid; q < L_; q += 256) {
    const float4* q4 = (const float4*)(Q + (((size_t)b * L_ + q) * H_ + h) * D_);
    float4 qv[16];
#pragma unroll
    for (int i = 0; i < 16; ++i) qv[i] = q4[i];
    float mx = -1e30f, smv = 0.f;
    for (int j = 0; j < SAMPK; ++j) {
      int kk = sample_idx(q * SAMPK + j, k2_0, k2_1);
      const float4* k4 = (const float4*)(K + (((size_t)b * L_ + kk) * H_ + h) * D_);
      float dot = 0.f;
#pragma unroll
      for (int i = 0; i < 16; ++i) {
        float4 kv = k4[i];
        dot += qv[i].x * kv.x + qv[i].y * kv.y + qv[i].z * kv.z + qv[i].w * kv.w;
      }
      mx = fmaxf(mx, dot);
      smv += dot;
    }
    sm[q] = mx - smv * (1.0f / (float)L_);
  }
  __syncthreads();

  // ---- Phase B: iterative top-38, tie -> lower index ----
  for (int u = 0; u < NTOP; ++u) {
    float bv = -1e38f; int bi = -1;
    for (int i = tid; i < L_; i += 256) {
      float v = sm[i];
      if (v > bv) { bv = v; bi = i; }   // ascending scan -> first hit = smallest idx
    }
    redv[tid] = bv; redi[tid] = bi;
    __syncthreads();
    for (int s = 128; s > 0; s >>= 1) {
      if (tid < s) {
        float v2 = redv[tid + s]; int i2 = redi[tid + s];
        if (v2 > redv[tid] ||
            (v2 == redv[tid] && i2 >= 0 && (redi[tid] < 0 || i2 < redi[tid]))) {
          redv[tid] = v2; redi[tid] = i2;
        }
      }
      __syncthreads();
    }
    if (tid == 0) {
      int sel = redi[0];
      if (sel < 0) sel = 0;             // defensive
      mtop_s[u] = sel;
      sm[sel] = -1e38f;
    }
    __syncthreads();
  }

  // ---- Phase C: causal softmax attention for each selected row (overwrite out) ----
  for (int u = 0; u < NTOP; ++u) {
    int pos = mtop_s[u];
    if (pos < 0) pos = 0;
    if (pos > L_ - 1) pos = L_ - 1;
    int klen = pos + 1;

    __syncthreads();
    if (tid < D_)
      qs[tid] = Q[(((size_t)b * L_ + pos) * H_ + h) * D_ + tid];
    __syncthreads();

    float lmax = -1e30f;
    for (int k = tid; k < klen; k += 256) {
      const float4* k4 = (const float4*)(K + (((size_t)b * L_ + k) * H_ + h) * D_);
      float dot = 0.f;
#pragma unroll
      for (int i = 0; i < 16; ++i) {
        float4 kv = k4[i];
        dot += qs[4 * i] * kv.x + qs[4 * i + 1] * kv.y
             + qs[4 * i + 2] * kv.z + qs[4 * i + 3] * kv.w;
      }
      dot *= 0.125f;                // 1/sqrt(64)
      sm[k] = dot;
      lmax = fmaxf(lmax, dot);
    }
    redv[tid] = lmax;
    __syncthreads();
    for (int s = 128; s > 0; s >>= 1) {
      if (tid < s) redv[tid] = fmaxf(redv[tid], redv[tid + s]);
      __syncthreads();
    }
    float mx = redv[0];
    __syncthreads();

    float lsum = 0.f;
    for (int k = tid; k < klen; k += 256) {
      float p = expf(sm[k] - mx);
      sm[k] = p;
      lsum += p;
    }
    redv[tid] = lsum;
    __syncthreads();
    for (int s = 128; s > 0; s >>= 1) {
      if (tid < s) redv[tid] += redv[tid + s];
      __syncthreads();
    }
    float inv = 1.0f / redv[0];
    __syncthreads();

    int d = tid & 63, slice = tid >> 6;
    float acc = 0.f;
    for (int k = slice; k < klen; k += 4)
      acc += sm[k] * V[(((size_t)b * L_ + k) * H_ + h) * D_ + d];
    part[slice][d] = acc;
    __syncthreads();
    if (tid < D_) {
      float r = (part[0][tid] + part[1][tid]) + (part[2][tid] + part[3][tid]);
      out[(((size_t)b * L_ + pos) * H_ + h) * D_ + tid] = r * inv;
    }
  }
}

extern "C" void kernel_launch(void* const* d_in, const int* in_sizes, int n_in,
                              void* d_out, int out_size, void* d_ws, size_t ws_size,
                              hipStream_t stream) {
  const float* Q = (const float*)d_in[0];
  const float* K = (const float*)d_in[1];
  const float* V = (const float*)d_in[2];
  float* out = (float*)d_out;

  cumsum_kernel<<<B_ * H_, 1024, 0, stream>>>(V, out);
  fused_kernel<<<B_ * H_, 256, 0, stream>>>(Q, K, V, out);
}

// Round 11
// 360.702 us; speedup vs baseline: 6.6360x; 6.6360x over previous
//
#include <hip/hip_runtime.h>
#include <hip/hip_bf16.h>
#include <math.h>

// Problem constants (B,L,H,D fixed by setup_inputs; S == L)
#define B_   4
#define L_   2048
#define H_   8
#define D_   64
#define NTOP 38          // int(5*ln(2048)) = 38
#define SAMPK 38
#define NIDX (L_*SAMPK)  // 77824

// Verified RNG (r10 PASS): JAX partitionable threefry WITH randint key-split:
//   k2 = threefry((0,42), (0,1));  idx[t] = (y0^y1 @ (k2,(0,t))) & 2047.

// ---- d_ws layout (r1 crash re-diagnosed as OOB-write bug, not ws overflow) ----
#define WS_IDX_OFF  0                       // uint16 idx[77824]   = 155648 B
#define WS_M_OFF    155648                  // float  M[65536]     = 262144 B
#define WS_MTOP_OFF (155648 + 262144)       // int    mtop[32*38]  =   4864 B
#define WS_NEEDED   (WS_MTOP_OFF + 4864)    // 422656 B

// ---------------- Threefry-2x32 (standard 20-round, KAT-verified) ----------------
__device__ __forceinline__ uint32_t rotl32(uint32_t v, int d) {
  return (v << d) | (v >> (32 - d));
}

__device__ __forceinline__ void threefry2x32(uint32_t k0, uint32_t k1,
                                             uint32_t x0, uint32_t x1,
                                             uint32_t& y0, uint32_t& y1) {
  const uint32_t ks2 = k0 ^ k1 ^ 0x1BD11BDAu;
  const uint32_t ks[3] = {k0, k1, ks2};
  x0 += k0; x1 += k1;
  const int ra[4] = {13, 15, 26, 6};
  const int rb[4] = {17, 29, 16, 24};
#pragma unroll
  for (int g = 0; g < 5; ++g) {
    const int* r = (g & 1) ? rb : ra;
#pragma unroll
    for (int i = 0; i < 4; ++i) {
      x0 += x1;
      x1 = rotl32(x1, r[i]);
      x1 ^= x0;
    }
    x0 += ks[(g + 1) % 3];
    x1 += ks[(g + 2) % 3] + (uint32_t)(g + 1);
  }
  y0 = x0; y1 = x1;
}

__device__ __forceinline__ int sample_idx(int t) {
  uint32_t k2_0, k2_1, y0, y1;
  threefry2x32(0u, 42u, 0u, 1u, k2_0, k2_1);          // k2 = split(key(42))[1]
  threefry2x32(k2_0, k2_1, 0u, (uint32_t)t, y0, y1);  // partitionable draw
  return (int)((y0 ^ y1) & 2047u);
}

// ---------------- k0: index stream (once, shared by all b,h) ----------------
__global__ __launch_bounds__(256) void gen_idx_kernel(uint16_t* __restrict__ idx) {
  int t = blockIdx.x * 256 + threadIdx.x;
  if (t < NIDX) idx[t] = (uint16_t)sample_idx(t);
}

// ---------------- k1: M[b,h,q] = max_j(q.k_j) - sum_j(q.k_j)/S ----------------
__global__ __launch_bounds__(256) void m_kernel(const float* __restrict__ Q,
                                                const float* __restrict__ K,
                                                const uint16_t* __restrict__ idx,
                                                float* __restrict__ M) {
  int t = blockIdx.x * 256 + threadIdx.x;   // t = (b*H + h)*L + q, 65536 total
  int q = t & (L_ - 1);
  int bh = t >> 11;
  int h = bh & (H_ - 1), b = bh >> 3;
  const float4* q4 = (const float4*)(Q + (((size_t)b * L_ + q) * H_ + h) * D_);
  float4 qv[16];
#pragma unroll
  for (int i = 0; i < 16; ++i) qv[i] = q4[i];
  float mx = -1e30f, smv = 0.f;
  for (int j = 0; j < SAMPK; ++j) {
    int kk = (int)idx[q * SAMPK + j];
    const float4* k4 = (const float4*)(K + (((size_t)b * L_ + kk) * H_ + h) * D_);
    float dot = 0.f;
#pragma unroll
    for (int i = 0; i < 16; ++i) {
      float4 kv = k4[i];
      dot += qv[i].x * kv.x + qv[i].y * kv.y + qv[i].z * kv.z + qv[i].w * kv.w;
    }
    mx = fmaxf(mx, dot);
    smv += dot;
  }
  M[t] = mx - smv * (1.0f / (float)L_);
}

// ---------------- k2: iterative top-38 per (b,h), tie -> lower index ----------------
__global__ __launch_bounds__(256) void topk_kernel(const float* __restrict__ M,
                                                   int* __restrict__ mtop) {
  int bh = blockIdx.x;
  int tid = threadIdx.x;
  __shared__ float sm[L_];
  __shared__ float redv[256];
  __shared__ int   redi[256];
  const float* Mrow = M + (size_t)bh * L_;
  for (int i = tid; i < L_; i += 256) sm[i] = Mrow[i];
  __syncthreads();
  for (int u = 0; u < NTOP; ++u) {
    float bv = -1e38f; int bi = -1;
    for (int i = tid; i < L_; i += 256) {
      float v = sm[i];
      if (v > bv) { bv = v; bi = i; }   // ascending scan -> first hit = smallest idx
    }
    redv[tid] = bv; redi[tid] = bi;
    __syncthreads();
    for (int s = 128; s > 0; s >>= 1) {
      if (tid < s) {
        float v2 = redv[tid + s]; int i2 = redi[tid + s];
        if (v2 > redv[tid] ||
            (v2 == redv[tid] && i2 >= 0 && (redi[tid] < 0 || i2 < redi[tid]))) {
          redv[tid] = v2; redi[tid] = i2;
        }
      }
      __syncthreads();
    }
    if (tid == 0) {
      int sel = redi[0];
      if (sel < 0) sel = 0;             // defensive
      mtop[bh * NTOP + u] = sel;
      sm[sel] = -1e38f;
    }
    __syncthreads();
  }
}

// ---------------- k3: cumsum(V) along L -> out ----------------
__global__ __launch_bounds__(1024) void cumsum_kernel(const float* __restrict__ V,
                                                      float* __restrict__ out) {
  int bh = blockIdx.x;
  int h = bh % H_, b = bh / H_;
  int tid = threadIdx.x;
  int d = tid & 63;
  int c = tid >> 6;               // 16 chunks of 128
  const int CHUNK = L_ / 16;      // 128
  __shared__ float cs[16][D_];
  size_t base = (((size_t)b * L_) * H_ + h) * D_ + d;
  const size_t lstride = (size_t)H_ * D_;   // 512
  float s = 0.f;
  for (int l = c * CHUNK; l < (c + 1) * CHUNK; ++l)
    s += V[base + (size_t)l * lstride];
  cs[c][d] = s;
  __syncthreads();
  float run = 0.f;
  for (int cc = 0; cc < c; ++cc) run += cs[cc][d];
  for (int l = c * CHUNK; l < (c + 1) * CHUNK; ++l) {
    run += V[base + (size_t)l * lstride];
    out[base + (size_t)l * lstride] = run;
  }
}

// ---------------- k4: one block per selected row; overwrite out ----------------
__global__ __launch_bounds__(256) void attn_kernel(const float* __restrict__ Q,
                                                   const float* __restrict__ K,
                                                   const float* __restrict__ V,
                                                   const int* __restrict__ mtop,
                                                   float* __restrict__ out) {
  int wg = blockIdx.x;            // bh*NTOP + u
  int u  = wg % NTOP;
  int bh = wg / NTOP;
  int h = bh & (H_ - 1), b = bh >> 3;
  int tid = threadIdx.x;

  int pos = mtop[bh * NTOP + u];
  if (pos < 0) pos = 0;
  if (pos > L_ - 1) pos = L_ - 1;
  int klen = pos + 1;

  __shared__ float qs[D_];
  __shared__ float sc[L_];
  __shared__ float redv[256];
  __shared__ float part[4][D_];

  if (tid < D_)
    qs[tid] = Q[(((size_t)b * L_ + pos) * H_ + h) * D_ + tid];
  __syncthreads();

  float lmax = -1e30f;
  for (int k = tid; k < klen; k += 256) {
    const float4* k4 = (const float4*)(K + (((size_t)b * L_ + k) * H_ + h) * D_);
    float dot = 0.f;
#pragma unroll
    for (int i = 0; i < 16; ++i) {
      float4 kv = k4[i];
      dot += qs[4 * i] * kv.x + qs[4 * i + 1] * kv.y
           + qs[4 * i + 2] * kv.z + qs[4 * i + 3] * kv.w;
    }
    dot *= 0.125f;                // 1/sqrt(64)
    sc[k] = dot;
    lmax = fmaxf(lmax, dot);
  }
  redv[tid] = lmax;
  __syncthreads();
  for (int s = 128; s > 0; s >>= 1) {
    if (tid < s) redv[tid] = fmaxf(redv[tid], redv[tid + s]);
    __syncthreads();
  }
  float mx = redv[0];
  __syncthreads();

  float lsum = 0.f;
  for (int k = tid; k < klen; k += 256) {
    float p = expf(sc[k] - mx);
    sc[k] = p;
    lsum += p;
  }
  redv[tid] = lsum;
  __syncthreads();
  for (int s = 128; s > 0; s >>= 1) {
    if (tid < s) redv[tid] += redv[tid + s];
    __syncthreads();
  }
  float inv = 1.0f / redv[0];
  __syncthreads();

  int d = tid & 63, g = tid >> 6;
  float acc = 0.f;
#pragma unroll 4
  for (int k = g; k < klen; k += 4)
    acc += sc[k] * V[(((size_t)b * L_ + k) * H_ + h) * D_ + d];
  part[g][d] = acc;
  __syncthreads();
  if (tid < D_) {
    float r = (part[0][tid] + part[1][tid]) + (part[2][tid] + part[3][tid]);
    out[(((size_t)b * L_ + pos) * H_ + h) * D_ + tid] = r * inv;
  }
}

// ================= fallback: r10's passing fused kernel (zero scratch) =================
__global__ __launch_bounds__(256) void fused_kernel(const float* __restrict__ Q,
                                                    const float* __restrict__ K,
                                                    const float* __restrict__ V,
                                                    float* __restrict__ out) {
  int bh = blockIdx.x;
  int h = bh % H_, b = bh / H_;
  int tid = threadIdx.x;

  __shared__ float sm[L_];
  __shared__ float redv[256];
  __shared__ int   redi[256];
  __shared__ int   mtop_s[NTOP];
  __shared__ float qs[D_];
  __shared__ float part[4][D_];

  for (int q = tid; q < L_; q += 256) {
    const float4* q4 = (const float4*)(Q + (((size_t)b * L_ + q) * H_ + h) * D_);
    float4 qv[16];
#pragma unroll
    for (int i = 0; i < 16; ++i) qv[i] = q4[i];
    float mx = -1e30f, smv = 0.f;
    for (int j = 0; j < SAMPK; ++j) {
      int kk = sample_idx(q * SAMPK + j);
      const float4* k4 = (const float4*)(K + (((size_t)b * L_ + kk) * H_ + h) * D_);
      float dot = 0.f;
#pragma unroll
      for (int i = 0; i < 16; ++i) {
        float4 kv = k4[i];
        dot += qv[i].x * kv.x + qv[i].y * kv.y + qv[i].z * kv.z + qv[i].w * kv.w;
      }
      mx = fmaxf(mx, dot);
      smv += dot;
    }
    sm[q] = mx - smv * (1.0f / (float)L_);
  }
  __syncthreads();

  for (int u = 0; u < NTOP; ++u) {
    float bv = -1e38f; int bi = -1;
    for (int i = tid; i < L_; i += 256) {
      float v = sm[i];
      if (v > bv) { bv = v; bi = i; }
    }
    redv[tid] = bv; redi[tid] = bi;
    __syncthreads();
    for (int s = 128; s > 0; s >>= 1) {
      if (tid < s) {
        float v2 = redv[tid + s]; int i2 = redi[tid + s];
        if (v2 > redv[tid] ||
            (v2 == redv[tid] && i2 >= 0 && (redi[tid] < 0 || i2 < redi[tid]))) {
          redv[tid] = v2; redi[tid] = i2;
        }
      }
      __syncthreads();
    }
    if (tid == 0) {
      int sel = redi[0];
      if (sel < 0) sel = 0;
      mtop_s[u] = sel;
      sm[sel] = -1e38f;
    }
    __syncthreads();
  }

  for (int u = 0; u < NTOP; ++u) {
    int pos = mtop_s[u];
    if (pos < 0) pos = 0;
    if (pos > L_ - 1) pos = L_ - 1;
    int klen = pos + 1;

    __syncthreads();
    if (tid < D_)
      qs[tid] = Q[(((size_t)b * L_ + pos) * H_ + h) * D_ + tid];
    __syncthreads();

    float lmax = -1e30f;
    for (int k = tid; k < klen; k += 256) {
      const float4* k4 = (const float4*)(K + (((size_t)b * L_ + k) * H_ + h) * D_);
      float dot = 0.f;
#pragma unroll
      for (int i = 0; i < 16; ++i) {
        float4 kv = k4[i];
        dot += qs[4 * i] * kv.x + qs[4 * i + 1] * kv.y
             + qs[4 * i + 2] * kv.z + qs[4 * i + 3] * kv.w;
      }
      dot *= 0.125f;
      sm[k] = dot;
      lmax = fmaxf(lmax, dot);
    }
    redv[tid] = lmax;
    __syncthreads();
    for (int s = 128; s > 0; s >>= 1) {
      if (tid < s) redv[tid] = fmaxf(redv[tid], redv[tid + s]);
      __syncthreads();
    }
    float mx = redv[0];
    __syncthreads();

    float lsum = 0.f;
    for (int k = tid; k < klen; k += 256) {
      float p = expf(sm[k] - mx);
      sm[k] = p;
      lsum += p;
    }
    redv[tid] = lsum;
    __syncthreads();
    for (int s = 128; s > 0; s >>= 1) {
      if (tid < s) redv[tid] += redv[tid + s];
      __syncthreads();
    }
    float inv = 1.0f / redv[0];
    __syncthreads();

    int d = tid & 63, slice = tid >> 6;
    float acc = 0.f;
    for (int k = slice; k < klen; k += 4)
      acc += sm[k] * V[(((size_t)b * L_ + k) * H_ + h) * D_ + d];
    part[slice][d] = acc;
    __syncthreads();
    if (tid < D_) {
      float r = (part[0][tid] + part[1][tid]) + (part[2][tid] + part[3][tid]);
      out[(((size_t)b * L_ + pos) * H_ + h) * D_ + tid] = r * inv;
    }
  }
}

extern "C" void kernel_launch(void* const* d_in, const int* in_sizes, int n_in,
                              void* d_out, int out_size, void* d_ws, size_t ws_size,
                              hipStream_t stream) {
  const float* Q = (const float*)d_in[0];
  const float* K = (const float*)d_in[1];
  const float* V = (const float*)d_in[2];
  float* out = (float*)d_out;

  if (ws_size >= (size_t)WS_NEEDED) {
    // fast path: multi-kernel pipeline through d_ws
    char* ws = (char*)d_ws;
    uint16_t* idx = (uint16_t*)(ws + WS_IDX_OFF);
    float*    M   = (float*)(ws + WS_M_OFF);
    int*      mt  = (int*)(ws + WS_MTOP_OFF);

    gen_idx_kernel<<<(NIDX + 255) / 256, 256, 0, stream>>>(idx);
    m_kernel<<<(B_ * H_ * L_) / 256, 256, 0, stream>>>(Q, K, idx, M);
    topk_kernel<<<B_ * H_, 256, 0, stream>>>(M, mt);
    cumsum_kernel<<<B_ * H_, 1024, 0, stream>>>(V, out);
    attn_kernel<<<B_ * H_ * NTOP, 256, 0, stream>>>(Q, K, V, mt, out);
  } else {
    // fallback: r10's verified zero-scratch path
    cumsum_kernel<<<B_ * H_, 1024, 0, stream>>>(V, out);
    fused_kernel<<<B_ * H_, 256, 0, stream>>>(Q, K, V, out);
  }
}

// Round 12
// 293.716 us; speedup vs baseline: 8.1494x; 1.2281x over previous
//
#include <hip/hip_runtime.h>
#include <hip/hip_bf16.h>
#include <math.h>

// Problem constants (B,L,H,D fixed by setup_inputs; S == L)
#define B_   4
#define L_   2048
#define H_   8
#define D_   64
#define NTOP 38          // int(5*ln(2048)) = 38
#define SAMPK 38
#define NIDX (L_*SAMPK)  // 77824

// Verified RNG (r10 PASS): JAX partitionable threefry WITH randint key-split:
//   k2 = threefry((0,42), (0,1));  idx[t] = (y0^y1 @ (k2,(0,t))) & 2047.

// ---- d_ws layout ----
#define WS_IDX_OFF  0                       // uint16 idx[77824]   = 155648 B
#define WS_M_OFF    155648                  // float  M[65536]     = 262144 B
#define WS_MTOP_OFF (155648 + 262144)       // int    mtop[32*38]  =   4864 B
#define WS_NEEDED   (WS_MTOP_OFF + 4864)    // 422656 B

// ---------------- Threefry-2x32 (standard 20-round, KAT-verified) ----------------
__device__ __forceinline__ uint32_t rotl32(uint32_t v, int d) {
  return (v << d) | (v >> (32 - d));
}

__device__ __forceinline__ void threefry2x32(uint32_t k0, uint32_t k1,
                                             uint32_t x0, uint32_t x1,
                                             uint32_t& y0, uint32_t& y1) {
  const uint32_t ks2 = k0 ^ k1 ^ 0x1BD11BDAu;
  const uint32_t ks[3] = {k0, k1, ks2};
  x0 += k0; x1 += k1;
  const int ra[4] = {13, 15, 26, 6};
  const int rb[4] = {17, 29, 16, 24};
#pragma unroll
  for (int g = 0; g < 5; ++g) {
    const int* r = (g & 1) ? rb : ra;
#pragma unroll
    for (int i = 0; i < 4; ++i) {
      x0 += x1;
      x1 = rotl32(x1, r[i]);
      x1 ^= x0;
    }
    x0 += ks[(g + 1) % 3];
    x1 += ks[(g + 2) % 3] + (uint32_t)(g + 1);
  }
  y0 = x0; y1 = x1;
}

__device__ __forceinline__ int sample_idx(int t) {
  uint32_t k2_0, k2_1, y0, y1;
  threefry2x32(0u, 42u, 0u, 1u, k2_0, k2_1);          // k2 = split(key(42))[1]
  threefry2x32(k2_0, k2_1, 0u, (uint32_t)t, y0, y1);  // partitionable draw
  return (int)((y0 ^ y1) & 2047u);
}

// ---------------- k0: index stream (once, shared by all b,h) ----------------
__global__ __launch_bounds__(256) void gen_idx_kernel(uint16_t* __restrict__ idx) {
  int t = blockIdx.x * 256 + threadIdx.x;
  if (t < NIDX) idx[t] = (uint16_t)sample_idx(t);
}

// ---------------- k1: M[b,h,q] = max_j(q.k_j) - sum_j(q.k_j)/S ----------------
// 256 blocks, XCD-swizzled so all blocks of one bh share an XCD (L2 locality).
// __launch_bounds__(256,1): thread count caps occupancy at 1 wave/SIMD anyway,
// so spend VGPRs on a double-buffered K-row prefetch. The dot/max/sum
// EXPRESSION ORDER matches r11 exactly (M ranking is fp-order sensitive).
__global__ __launch_bounds__(256, 1) void m_kernel(const float* __restrict__ Q,
                                                   const float* __restrict__ K,
                                                   const uint16_t* __restrict__ idx,
                                                   float* __restrict__ M) {
  int bI = blockIdx.x;
  int j8 = bI >> 3;
  int bh = (bI & 7) + 8 * (j8 >> 3);    // blockIdx%8 == bh%8 -> same XCD
  int inner = j8 & 7;                    // 8 blocks of 256 q per bh
  int tid = threadIdx.x;
  int q = inner * 256 + tid;
  int h = bh & (H_ - 1), b = bh >> 3;

  const float4* q4 = (const float4*)(Q + (((size_t)b * L_ + q) * H_ + h) * D_);
  float4 qv[16];
#pragma unroll
  for (int i = 0; i < 16; ++i) qv[i] = q4[i];

  const float* Kbase = K + ((size_t)b * L_ * H_ + h) * D_;
  const uint16_t* irow = idx + q * SAMPK;

  float4 kva[16], kvb[16];
  {
    const float4* kp = (const float4*)(Kbase + (size_t)irow[0] * (H_ * D_));
#pragma unroll
    for (int i = 0; i < 16; ++i) kva[i] = kp[i];
  }

  float mx = -1e30f, smv = 0.f;
#define M_DOT(BUF)                                                        \
  {                                                                       \
    float dot = 0.f;                                                      \
    _Pragma("unroll")                                                     \
    for (int i = 0; i < 16; ++i) {                                        \
      float4 kv = BUF[i];                                                 \
      dot += qv[i].x * kv.x + qv[i].y * kv.y + qv[i].z * kv.z             \
           + qv[i].w * kv.w;                                              \
    }                                                                     \
    mx = fmaxf(mx, dot);                                                  \
    smv += dot;                                                           \
  }

  for (int jj = 0; jj < SAMPK; jj += 2) {
    // prefetch jj+1 into kvb
    {
      const float4* kp = (const float4*)(Kbase + (size_t)irow[jj + 1] * (H_ * D_));
#pragma unroll
      for (int i = 0; i < 16; ++i) kvb[i] = kp[i];
    }
    M_DOT(kva)          // consume jj
    // prefetch jj+2 into kva
    if (jj + 2 < SAMPK) {
      const float4* kp = (const float4*)(Kbase + (size_t)irow[jj + 2] * (H_ * D_));
#pragma unroll
      for (int i = 0; i < 16; ++i) kva[i] = kp[i];
    }
    M_DOT(kvb)          // consume jj+1
  }
#undef M_DOT

  M[(size_t)bh * L_ + q] = mx - smv * (1.0f / (float)L_);
}

// ---------------- k2: top-38 per (b,h) via cached per-thread candidates ----------------
__global__ __launch_bounds__(256) void topk_kernel(const float* __restrict__ M,
                                                   int* __restrict__ mtop) {
  int bh = blockIdx.x;
  int tid = threadIdx.x;
  __shared__ float sm[L_];
  __shared__ float wv[4];
  __shared__ int   wi[4];
  __shared__ int   ssel;
  const float* Mrow = M + (size_t)bh * L_;
  for (int i = tid; i < L_; i += 256) sm[i] = Mrow[i];
  __syncthreads();

  // per-thread cached best over its strided slice (ascending -> lowest idx on tie)
  float bv = -1e38f; int bi = -1;
  for (int i = tid; i < L_; i += 256) {
    float v = sm[i];
    if (v > bv) { bv = v; bi = i; }
  }

  int lane = tid & 63, wid = tid >> 6;
  for (int u = 0; u < NTOP; ++u) {
    // wave shuffle reduce (max, tie -> lower index)
    float v = bv; int i = bi;
#pragma unroll
    for (int off = 32; off > 0; off >>= 1) {
      float v2 = __shfl_down(v, off);
      int   i2 = __shfl_down(i, off);
      if (v2 > v || (v2 == v && i2 >= 0 && (i < 0 || i2 < i))) { v = v2; i = i2; }
    }
    if (lane == 0) { wv[wid] = v; wi[wid] = i; }
    __syncthreads();
    if (tid == 0) {
      float fv = wv[0]; int fi = wi[0];
#pragma unroll
      for (int w = 1; w < 4; ++w) {
        if (wv[w] > fv || (wv[w] == fv && wi[w] >= 0 && (fi < 0 || wi[w] < fi))) {
          fv = wv[w]; fi = wi[w];
        }
      }
      if (fi < 0) fi = 0;
      mtop[bh * NTOP + u] = fi;
      sm[fi] = -1e38f;
      ssel = fi;
    }
    __syncthreads();
    int sel = ssel;
    if (bi == sel) {        // only the winner's owner rescans its 8-element slice
      bv = -1e38f; bi = -1;
      for (int i2 = tid; i2 < L_; i2 += 256) {
        float vv = sm[i2];
        if (vv > bv) { bv = vv; bi = i2; }
      }
    }
  }
}

// ---------------- k3: cumsum(V) along L -> out (64 blocks: bh x d-half) ----------------
__global__ __launch_bounds__(1024) void cumsum_kernel(const float* __restrict__ V,
                                                      float* __restrict__ out) {
  int bI = blockIdx.x;            // 64 blocks
  int bh = bI >> 1, dhalf = bI & 1;
  int h = bh & (H_ - 1), b = bh >> 3;
  int tid = threadIdx.x;
  int dl = tid & 31, c = tid >> 5;     // 32 chunks of 64
  int d = dhalf * 32 + dl;
  const int CH = L_ / 32;              // 64
  __shared__ float cs[32][32];
  size_t base = ((size_t)b * L_ * H_ + h) * D_ + d;
  const size_t ls = (size_t)H_ * D_;   // 512
  float s = 0.f;
  for (int l = c * CH; l < (c + 1) * CH; ++l)
    s += V[base + (size_t)l * ls];
  cs[c][dl] = s;
  __syncthreads();
  float run = 0.f;
  for (int cc = 0; cc < c; ++cc) run += cs[cc][dl];
  for (int l = c * CH; l < (c + 1) * CH; ++l) {
    run += V[base + (size_t)l * ls];
    out[base + (size_t)l * ls] = run;
  }
}

// ---------------- k4: one block per selected row; overwrite out ----------------
// XCD-swizzled (blockIdx%8 == bh%8). PV pass: 16 groups x 16 threads, float4.
__global__ __launch_bounds__(256) void attn_kernel(const float* __restrict__ Q,
                                                   const float* __restrict__ K,
                                                   const float* __restrict__ V,
                                                   const int* __restrict__ mtop,
                                                   float* __restrict__ out) {
  int bI = blockIdx.x;            // 1216 = 8 * 152
  int j = bI >> 3;                // 0..151
  int u = j % NTOP;
  int bh = (bI & 7) + 8 * (j / NTOP);
  int h = bh & (H_ - 1), b = bh >> 3;
  int tid = threadIdx.x;

  int pos = mtop[bh * NTOP + u];
  if (pos < 0) pos = 0;
  if (pos > L_ - 1) pos = L_ - 1;
  int klen = pos + 1;

  __shared__ float qs[D_];
  __shared__ float sc[L_];
  __shared__ float redv[256];
  __shared__ float4 part4[16][16];

  if (tid < D_)
    qs[tid] = Q[(((size_t)b * L_ + pos) * H_ + h) * D_ + tid];
  __syncthreads();

  // QK^T * scale + running max
  float lmax = -1e30f;
  for (int k = tid; k < klen; k += 256) {
    const float4* k4 = (const float4*)(K + (((size_t)b * L_ + k) * H_ + h) * D_);
    float dot = 0.f;
#pragma unroll
    for (int i = 0; i < 16; ++i) {
      float4 kv = k4[i];
      dot += qs[4 * i] * kv.x + qs[4 * i + 1] * kv.y
           + qs[4 * i + 2] * kv.z + qs[4 * i + 3] * kv.w;
    }
    dot *= 0.125f;                // 1/sqrt(64)
    sc[k] = dot;
    lmax = fmaxf(lmax, dot);
  }
  redv[tid] = lmax;
  __syncthreads();
  for (int s = 128; s > 0; s >>= 1) {
    if (tid < s) redv[tid] = fmaxf(redv[tid], redv[tid + s]);
    __syncthreads();
  }
  float mx = redv[0];
  __syncthreads();

  // exp + sum
  float lsum = 0.f;
  for (int k = tid; k < klen; k += 256) {
    float p = expf(sc[k] - mx);
    sc[k] = p;
    lsum += p;
  }
  redv[tid] = lsum;
  __syncthreads();
  for (int s = 128; s > 0; s >>= 1) {
    if (tid < s) redv[tid] += redv[tid + s];
    __syncthreads();
  }
  float inv = 1.0f / redv[0];
  __syncthreads();

  // PV: group g handles rows k = g, g+16, ...; thread owns d-quad t16 (float4)
  int t16 = tid & 15, g = tid >> 4;
  float4 acc = make_float4(0.f, 0.f, 0.f, 0.f);
  const float* Vbase = V + ((size_t)b * L_ * H_ + h) * D_ + 4 * t16;
  for (int k = g; k < klen; k += 16) {
    float p = sc[k];
    float4 v4 = *(const float4*)(Vbase + (size_t)k * (H_ * D_));
    acc.x += p * v4.x; acc.y += p * v4.y; acc.z += p * v4.z; acc.w += p * v4.w;
  }
  part4[g][t16] = acc;
  __syncthreads();
#pragma unroll
  for (int s = 8; s > 0; s >>= 1) {
    if (g < s) {
      float4 o = part4[g + s][t16];
      float4 m = part4[g][t16];
      m.x += o.x; m.y += o.y; m.z += o.z; m.w += o.w;
      part4[g][t16] = m;
    }
    __syncthreads();
  }
  if (tid < 16) {
    float4 r = part4[0][tid];
    r.x *= inv; r.y *= inv; r.z *= inv; r.w *= inv;
    *(float4*)(out + (((size_t)b * L_ + pos) * H_ + h) * D_ + 4 * tid) = r;
  }
}

// ================= fallback: r10's passing fused kernel (zero scratch) =================
__global__ __launch_bounds__(256) void fused_kernel(const float* __restrict__ Q,
                                                    const float* __restrict__ K,
                                                    const float* __restrict__ V,
                                                    float* __restrict__ out) {
  int bh = blockIdx.x;
  int h = bh % H_, b = bh / H_;
  int tid = threadIdx.x;

  __shared__ float sm[L_];
  __shared__ float redv[256];
  __shared__ int   redi[256];
  __shared__ int   mtop_s[NTOP];
  __shared__ float qs[D_];
  __shared__ float part[4][D_];

  for (int q = tid; q < L_; q += 256) {
    const float4* q4 = (const float4*)(Q + (((size_t)b * L_ + q) * H_ + h) * D_);
    float4 qv[16];
#pragma unroll
    for (int i = 0; i < 16; ++i) qv[i] = q4[i];
    float mx = -1e30f, smv = 0.f;
    for (int j = 0; j < SAMPK; ++j) {
      int kk = sample_idx(q * SAMPK + j);
      const float4* k4 = (const float4*)(K + (((size_t)b * L_ + kk) * H_ + h) * D_);
      float dot = 0.f;
#pragma unroll
      for (int i = 0; i < 16; ++i) {
        float4 kv = k4[i];
        dot += qv[i].x * kv.x + qv[i].y * kv.y + qv[i].z * kv.z + qv[i].w * kv.w;
      }
      mx = fmaxf(mx, dot);
      smv += dot;
    }
    sm[q] = mx - smv * (1.0f / (float)L_);
  }
  __syncthreads();

  for (int u = 0; u < NTOP; ++u) {
    float bv = -1e38f; int bi = -1;
    for (int i = tid; i < L_; i += 256) {
      float v = sm[i];
      if (v > bv) { bv = v; bi = i; }
    }
    redv[tid] = bv; redi[tid] = bi;
    __syncthreads();
    for (int s = 128; s > 0; s >>= 1) {
      if (tid < s) {
        float v2 = redv[tid + s]; int i2 = redi[tid + s];
        if (v2 > redv[tid] ||
            (v2 == redv[tid] && i2 >= 0 && (redi[tid] < 0 || i2 < redi[tid]))) {
          redv[tid] = v2; redi[tid] = i2;
        }
      }
      __syncthreads();
    }
    if (tid == 0) {
      int sel = redi[0];
      if (sel < 0) sel = 0;
      mtop_s[u] = sel;
      sm[sel] = -1e38f;
    }
    __syncthreads();
  }

  for (int u = 0; u < NTOP; ++u) {
    int pos = mtop_s[u];
    if (pos < 0) pos = 0;
    if (pos > L_ - 1) pos = L_ - 1;
    int klen = pos + 1;

    __syncthreads();
    if (tid < D_)
      qs[tid] = Q[(((size_t)b * L_ + pos) * H_ + h) * D_ + tid];
    __syncthreads();

    float lmax = -1e30f;
    for (int k = tid; k < klen; k += 256) {
      const float4* k4 = (const float4*)(K + (((size_t)b * L_ + k) * H_ + h) * D_);
      float dot = 0.f;
#pragma unroll
      for (int i = 0; i < 16; ++i) {
        float4 kv = k4[i];
        dot += qs[4 * i] * kv.x + qs[4 * i + 1] * kv.y
             + qs[4 * i + 2] * kv.z + qs[4 * i + 3] * kv.w;
      }
      dot *= 0.125f;
      sm[k] = dot;
      lmax = fmaxf(lmax, dot);
    }
    redv[tid] = lmax;
    __syncthreads();
    for (int s = 128; s > 0; s >>= 1) {
      if (tid < s) redv[tid] = fmaxf(redv[tid], redv[tid + s]);
      __syncthreads();
    }
    float mx = redv[0];
    __syncthreads();

    float lsum = 0.f;
    for (int k = tid; k < klen; k += 256) {
      float p = expf(sm[k] - mx);
      sm[k] = p;
      lsum += p;
    }
    redv[tid] = lsum;
    __syncthreads();
    for (int s = 128; s > 0; s >>= 1) {
      if (tid < s) redv[tid] += redv[tid + s];
      __syncthreads();
    }
    float inv = 1.0f / redv[0];
    __syncthreads();

    int d = tid & 63, slice = tid >> 6;
    float acc = 0.f;
    for (int k = slice; k < klen; k += 4)
      acc += sm[k] * V[(((size_t)b * L_ + k) * H_ + h) * D_ + d];
    part[slice][d] = acc;
    __syncthreads();
    if (tid < D_) {
      float r = (part[0][tid] + part[1][tid]) + (part[2][tid] + part[3][tid]);
      out[(((size_t)b * L_ + pos) * H_ + h) * D_ + tid] = r * inv;
    }
  }
}

extern "C" void kernel_launch(void* const* d_in, const int* in_sizes, int n_in,
                              void* d_out, int out_size, void* d_ws, size_t ws_size,
                              hipStream_t stream) {
  const float* Q = (const float*)d_in[0];
  const float* K = (const float*)d_in[1];
  const float* V = (const float*)d_in[2];
  float* out = (float*)d_out;

  if (ws_size >= (size_t)WS_NEEDED) {
    char* ws = (char*)d_ws;
    uint16_t* idx = (uint16_t*)(ws + WS_IDX_OFF);
    float*    M   = (float*)(ws + WS_M_OFF);
    int*      mt  = (int*)(ws + WS_MTOP_OFF);

    gen_idx_kernel<<<(NIDX + 255) / 256, 256, 0, stream>>>(idx);
    m_kernel<<<B_ * H_ * L_ / 256, 256, 0, stream>>>(Q, K, idx, M);
    topk_kernel<<<B_ * H_, 256, 0, stream>>>(M, mt);
    cumsum_kernel<<<B_ * H_ * 2, 1024, 0, stream>>>(V, out);
    attn_kernel<<<B_ * H_ * NTOP, 256, 0, stream>>>(Q, K, V, mt, out);
  } else {
    cumsum_kernel<<<B_ * H_ * 2, 1024, 0, stream>>>(V, out);
    fused_kernel<<<B_ * H_, 256, 0, stream>>>(Q, K, V, out);
  }
}

// Round 13
// 247.058 us; speedup vs baseline: 9.6884x; 1.1889x over previous
//
#include <hip/hip_runtime.h>
#include <hip/hip_bf16.h>
#include <math.h>

// Problem constants (B,L,H,D fixed by setup_inputs; S == L)
#define B_   4
#define L_   2048
#define H_   8
#define D_   64
#define NTOP 38          // int(5*ln(2048)) = 38
#define SAMPK 38
#define NIDX (L_*SAMPK)  // 77824

// Verified RNG (r10 PASS): JAX partitionable threefry WITH randint key-split:
//   k2 = threefry((0,42), (0,1));  idx[t] = (y0^y1 @ (k2,(0,t))) & 2047.

// ---- d_ws layout (idx buffer eliminated in r13 — threefry inlined in m_kernel) ----
#define WS_M_OFF    0                       // float  M[65536]     = 262144 B
#define WS_MTOP_OFF 262144                  // int    mtop[32*38]  =   4864 B
#define WS_NEEDED   (WS_MTOP_OFF + 4864)    // 267008 B

// ---------------- Threefry-2x32 (standard 20-round, KAT-verified) ----------------
__device__ __forceinline__ uint32_t rotl32(uint32_t v, int d) {
  return (v << d) | (v >> (32 - d));
}

__device__ __forceinline__ void threefry2x32(uint32_t k0, uint32_t k1,
                                             uint32_t x0, uint32_t x1,
                                             uint32_t& y0, uint32_t& y1) {
  const uint32_t ks2 = k0 ^ k1 ^ 0x1BD11BDAu;
  const uint32_t ks[3] = {k0, k1, ks2};
  x0 += k0; x1 += k1;
  const int ra[4] = {13, 15, 26, 6};
  const int rb[4] = {17, 29, 16, 24};
#pragma unroll
  for (int g = 0; g < 5; ++g) {
    const int* r = (g & 1) ? rb : ra;
#pragma unroll
    for (int i = 0; i < 4; ++i) {
      x0 += x1;
      x1 = rotl32(x1, r[i]);
      x1 ^= x0;
    }
    x0 += ks[(g + 1) % 3];
    x1 += ks[(g + 2) % 3] + (uint32_t)(g + 1);
  }
  y0 = x0; y1 = x1;
}

__device__ __forceinline__ int sample_idx(int t) {
  uint32_t k2_0, k2_1, y0, y1;
  threefry2x32(0u, 42u, 0u, 1u, k2_0, k2_1);          // k2 = split(key(42))[1]
  threefry2x32(k2_0, k2_1, 0u, (uint32_t)t, y0, y1);  // partitionable draw
  return (int)((y0 ^ y1) & 2047u);
}

// ---------------- k1: M[b,h,q] = max_j(q.k_j) - sum_j(q.k_j)/S ----------------
// 4096 blocks (16 q each), 16 lanes per q -> coalesced K gathers (4 lines/instr
// vs 64 for thread-per-row), 16x more blocks for latency hiding. Threefry
// inlined (608 idx/block staged in LDS). Dot = lane-partial(x,y,z,w) + 16-lane
// butterfly; j-loop max/sum order unchanged.
__global__ __launch_bounds__(256) void m_kernel(const float* __restrict__ Q,
                                                const float* __restrict__ K,
                                                float* __restrict__ M) {
  int bI = blockIdx.x;                  // 4096 = 8 * 512
  int j8 = bI >> 3;                     // 0..511
  int bh = (bI & 7) + 8 * (j8 >> 7);    // blockIdx%8 == bh%8 -> same XCD
  int chunk = j8 & 127;                 // 128 chunks of 16 q per bh
  int tid = threadIdx.x;
  int grp = tid >> 4, c = tid & 15;     // 16 groups x 16 lanes
  int q = chunk * 16 + grp;
  int h = bh & (H_ - 1), b = bh >> 3;

  __shared__ uint16_t sidx[16][SAMPK];
  for (int s = tid; s < 16 * SAMPK; s += 256) {
    int ql = s / SAMPK, jj = s - ql * SAMPK;
    sidx[ql][jj] = (uint16_t)sample_idx((chunk * 16 + ql) * SAMPK + jj);
  }
  __syncthreads();

  float4 qv = *(const float4*)(Q + (((size_t)b * L_ + q) * H_ + h) * D_ + 4 * c);
  const float* Kbase = K + ((size_t)b * L_ * H_ + h) * D_ + 4 * c;

  float mx = -1e30f, smv = 0.f;
  for (int j = 0; j < SAMPK; ++j) {
    int row = (int)sidx[grp][j];
    float4 kv = *(const float4*)(Kbase + (size_t)row * (H_ * D_));
    float part = qv.x * kv.x + qv.y * kv.y + qv.z * kv.z + qv.w * kv.w;
#pragma unroll
    for (int off = 1; off < 16; off <<= 1)
      part += __shfl_xor(part, off);
    mx = fmaxf(mx, part);
    smv += part;
  }
  if (c == 0)
    M[(size_t)bh * L_ + q] = mx - smv * (1.0f / (float)L_);
}

// ---------------- k2: top-38 per (b,h) via cached per-thread candidates ----------------
__global__ __launch_bounds__(256) void topk_kernel(const float* __restrict__ M,
                                                   int* __restrict__ mtop) {
  int bh = blockIdx.x;
  int tid = threadIdx.x;
  __shared__ float sm[L_];
  __shared__ float wv[4];
  __shared__ int   wi[4];
  __shared__ int   ssel;
  const float* Mrow = M + (size_t)bh * L_;
  for (int i = tid; i < L_; i += 256) sm[i] = Mrow[i];
  __syncthreads();

  float bv = -1e38f; int bi = -1;
  for (int i = tid; i < L_; i += 256) {
    float v = sm[i];
    if (v > bv) { bv = v; bi = i; }     // ascending -> lowest idx on tie
  }

  int lane = tid & 63, wid = tid >> 6;
  for (int u = 0; u < NTOP; ++u) {
    float v = bv; int i = bi;
#pragma unroll
    for (int off = 32; off > 0; off >>= 1) {
      float v2 = __shfl_down(v, off);
      int   i2 = __shfl_down(i, off);
      if (v2 > v || (v2 == v && i2 >= 0 && (i < 0 || i2 < i))) { v = v2; i = i2; }
    }
    if (lane == 0) { wv[wid] = v; wi[wid] = i; }
    __syncthreads();
    if (tid == 0) {
      float fv = wv[0]; int fi = wi[0];
#pragma unroll
      for (int w = 1; w < 4; ++w) {
        if (wv[w] > fv || (wv[w] == fv && wi[w] >= 0 && (fi < 0 || wi[w] < fi))) {
          fv = wv[w]; fi = wi[w];
        }
      }
      if (fi < 0) fi = 0;
      mtop[bh * NTOP + u] = fi;
      sm[fi] = -1e38f;
      ssel = fi;
    }
    __syncthreads();
    int sel = ssel;
    if (bi == sel) {        // only the winner's owner rescans its slice
      bv = -1e38f; bi = -1;
      for (int i2 = tid; i2 < L_; i2 += 256) {
        float vv = sm[i2];
        if (vv > bv) { bv = vv; bi = i2; }
      }
    }
  }
}

// ---------------- k3: cumsum(V) along L -> out (64 blocks: bh x d-half) ----------------
__global__ __launch_bounds__(1024) void cumsum_kernel(const float* __restrict__ V,
                                                      float* __restrict__ out) {
  int bI = blockIdx.x;            // 64 blocks
  int bh = bI >> 1, dhalf = bI & 1;
  int h = bh & (H_ - 1), b = bh >> 3;
  int tid = threadIdx.x;
  int dl = tid & 31, c = tid >> 5;     // 32 chunks of 64
  int d = dhalf * 32 + dl;
  const int CH = L_ / 32;              // 64
  __shared__ float cs[32][32];
  size_t base = ((size_t)b * L_ * H_ + h) * D_ + d;
  const size_t ls = (size_t)H_ * D_;   // 512
  float s = 0.f;
  for (int l = c * CH; l < (c + 1) * CH; ++l)
    s += V[base + (size_t)l * ls];
  cs[c][dl] = s;
  __syncthreads();
  float run = 0.f;
  for (int cc = 0; cc < c; ++cc) run += cs[cc][dl];
  for (int l = c * CH; l < (c + 1) * CH; ++l) {
    run += V[base + (size_t)l * ls];
    out[base + (size_t)l * ls] = run;
  }
}

// ---------------- k4: one block per selected row; overwrite out ----------------
// QK pass: 16 lanes per K row (coalesced) + butterfly dot-reduce. PV: float4.
__global__ __launch_bounds__(256) void attn_kernel(const float* __restrict__ Q,
                                                   const float* __restrict__ K,
                                                   const float* __restrict__ V,
                                                   const int* __restrict__ mtop,
                                                   float* __restrict__ out) {
  int bI = blockIdx.x;            // 1216 = 8 * 152
  int j = bI >> 3;                // 0..151
  int u = j % NTOP;
  int bh = (bI & 7) + 8 * (j / NTOP);
  int h = bh & (H_ - 1), b = bh >> 3;
  int tid = threadIdx.x;

  int pos = mtop[bh * NTOP + u];
  if (pos < 0) pos = 0;
  if (pos > L_ - 1) pos = L_ - 1;
  int klen = pos + 1;

  __shared__ float qs[D_];
  __shared__ float sc[L_];
  __shared__ float redv[256];
  __shared__ float4 part4[16][16];

  if (tid < D_)
    qs[tid] = Q[(((size_t)b * L_ + pos) * H_ + h) * D_ + tid];
  __syncthreads();

  // QK^T * scale + running max: group g owns rows k = g, g+16, ...
  int c16 = tid & 15, g = tid >> 4;
  float4 qreg = *(const float4*)(qs + 4 * c16);
  const float* Kbase = K + ((size_t)b * L_ * H_ + h) * D_ + 4 * c16;
  float lmax = -1e30f;
  for (int k = g; k < klen; k += 16) {
    float4 kv = *(const float4*)(Kbase + (size_t)k * (H_ * D_));
    float part = qreg.x * kv.x + qreg.y * kv.y + qreg.z * kv.z + qreg.w * kv.w;
#pragma unroll
    for (int off = 1; off < 16; off <<= 1)
      part += __shfl_xor(part, off);
    part *= 0.125f;               // 1/sqrt(64)
    if (c16 == 0) sc[k] = part;
    lmax = fmaxf(lmax, part);
  }
  redv[tid] = lmax;
  __syncthreads();
  for (int s = 128; s > 0; s >>= 1) {
    if (tid < s) redv[tid] = fmaxf(redv[tid], redv[tid + s]);
    __syncthreads();
  }
  float mx = redv[0];
  __syncthreads();

  // exp + sum (thread-per-k from LDS)
  float lsum = 0.f;
  for (int k = tid; k < klen; k += 256) {
    float p = expf(sc[k] - mx);
    sc[k] = p;
    lsum += p;
  }
  redv[tid] = lsum;
  __syncthreads();
  for (int s = 128; s > 0; s >>= 1) {
    if (tid < s) redv[tid] += redv[tid + s];
    __syncthreads();
  }
  float inv = 1.0f / redv[0];
  __syncthreads();

  // PV: group g handles rows k = g, g+16, ...; thread owns d-quad c16 (float4)
  float4 acc = make_float4(0.f, 0.f, 0.f, 0.f);
  const float* Vbase = V + ((size_t)b * L_ * H_ + h) * D_ + 4 * c16;
  for (int k = g; k < klen; k += 16) {
    float p = sc[k];
    float4 v4 = *(const float4*)(Vbase + (size_t)k * (H_ * D_));
    acc.x += p * v4.x; acc.y += p * v4.y; acc.z += p * v4.z; acc.w += p * v4.w;
  }
  part4[g][c16] = acc;
  __syncthreads();
#pragma unroll
  for (int s = 8; s > 0; s >>= 1) {
    if (g < s) {
      float4 o = part4[g + s][c16];
      float4 m = part4[g][c16];
      m.x += o.x; m.y += o.y; m.z += o.z; m.w += o.w;
      part4[g][c16] = m;
    }
    __syncthreads();
  }
  if (tid < 16) {
    float4 r = part4[0][tid];
    r.x *= inv; r.y *= inv; r.z *= inv; r.w *= inv;
    *(float4*)(out + (((size_t)b * L_ + pos) * H_ + h) * D_ + 4 * tid) = r;
  }
}

// ================= fallback: r10's passing fused kernel (zero scratch) =================
__global__ __launch_bounds__(256) void fused_kernel(const float* __restrict__ Q,
                                                    const float* __restrict__ K,
                                                    const float* __restrict__ V,
                                                    float* __restrict__ out) {
  int bh = blockIdx.x;
  int h = bh % H_, b = bh / H_;
  int tid = threadIdx.x;

  __shared__ float sm[L_];
  __shared__ float redv[256];
  __shared__ int   redi[256];
  __shared__ int   mtop_s[NTOP];
  __shared__ float qs[D_];
  __shared__ float part[4][D_];

  for (int q = tid; q < L_; q += 256) {
    const float4* q4 = (const float4*)(Q + (((size_t)b * L_ + q) * H_ + h) * D_);
    float4 qv[16];
#pragma unroll
    for (int i = 0; i < 16; ++i) qv[i] = q4[i];
    float mx = -1e30f, smv = 0.f;
    for (int j = 0; j < SAMPK; ++j) {
      int kk = sample_idx(q * SAMPK + j);
      const float4* k4 = (const float4*)(K + (((size_t)b * L_ + kk) * H_ + h) * D_);
      float dot = 0.f;
#pragma unroll
      for (int i = 0; i < 16; ++i) {
        float4 kv = k4[i];
        dot += qv[i].x * kv.x + qv[i].y * kv.y + qv[i].z * kv.z + qv[i].w * kv.w;
      }
      mx = fmaxf(mx, dot);
      smv += dot;
    }
    sm[q] = mx - smv * (1.0f / (float)L_);
  }
  __syncthreads();

  for (int u = 0; u < NTOP; ++u) {
    float bv = -1e38f; int bi = -1;
    for (int i = tid; i < L_; i += 256) {
      float v = sm[i];
      if (v > bv) { bv = v; bi = i; }
    }
    redv[tid] = bv; redi[tid] = bi;
    __syncthreads();
    for (int s = 128; s > 0; s >>= 1) {
      if (tid < s) {
        float v2 = redv[tid + s]; int i2 = redi[tid + s];
        if (v2 > redv[tid] ||
            (v2 == redv[tid] && i2 >= 0 && (redi[tid] < 0 || i2 < redi[tid]))) {
          redv[tid] = v2; redi[tid] = i2;
        }
      }
      __syncthreads();
    }
    if (tid == 0) {
      int sel = redi[0];
      if (sel < 0) sel = 0;
      mtop_s[u] = sel;
      sm[sel] = -1e38f;
    }
    __syncthreads();
  }

  for (int u = 0; u < NTOP; ++u) {
    int pos = mtop_s[u];
    if (pos < 0) pos = 0;
    if (pos > L_ - 1) pos = L_ - 1;
    int klen = pos + 1;

    __syncthreads();
    if (tid < D_)
      qs[tid] = Q[(((size_t)b * L_ + pos) * H_ + h) * D_ + tid];
    __syncthreads();

    float lmax = -1e30f;
    for (int k = tid; k < klen; k += 256) {
      const float4* k4 = (const float4*)(K + (((size_t)b * L_ + k) * H_ + h) * D_);
      float dot = 0.f;
#pragma unroll
      for (int i = 0; i < 16; ++i) {
        float4 kv = k4[i];
        dot += qs[4 * i] * kv.x + qs[4 * i + 1] * kv.y
             + qs[4 * i + 2] * kv.z + qs[4 * i + 3] * kv.w;
      }
      dot *= 0.125f;
      sm[k] = dot;
      lmax = fmaxf(lmax, dot);
    }
    redv[tid] = lmax;
    __syncthreads();
    for (int s = 128; s > 0; s >>= 1) {
      if (tid < s) redv[tid] = fmaxf(redv[tid], redv[tid + s]);
      __syncthreads();
    }
    float mx = redv[0];
    __syncthreads();

    float lsum = 0.f;
    for (int k = tid; k < klen; k += 256) {
      float p = expf(sm[k] - mx);
      sm[k] = p;
      lsum += p;
    }
    redv[tid] = lsum;
    __syncthreads();
    for (int s = 128; s > 0; s >>= 1) {
      if (tid < s) redv[tid] += redv[tid + s];
      __syncthreads();
    }
    float inv = 1.0f / redv[0];
    __syncthreads();

    int d = tid & 63, slice = tid >> 6;
    float acc = 0.f;
    for (int k = slice; k < klen; k += 4)
      acc += sm[k] * V[(((size_t)b * L_ + k) * H_ + h) * D_ + d];
    part[slice][d] = acc;
    __syncthreads();
    if (tid < D_) {
      float r = (part[0][tid] + part[1][tid]) + (part[2][tid] + part[3][tid]);
      out[(((size_t)b * L_ + pos) * H_ + h) * D_ + tid] = r * inv;
    }
  }
}

extern "C" void kernel_launch(void* const* d_in, const int* in_sizes, int n_in,
                              void* d_out, int out_size, void* d_ws, size_t ws_size,
                              hipStream_t stream) {
  const float* Q = (const float*)d_in[0];
  const float* K = (const float*)d_in[1];
  const float* V = (const float*)d_in[2];
  float* out = (float*)d_out;

  if (ws_size >= (size_t)WS_NEEDED) {
    char* ws = (char*)d_ws;
    float* M  = (float*)(ws + WS_M_OFF);
    int*   mt = (int*)(ws + WS_MTOP_OFF);

    m_kernel<<<4096, 256, 0, stream>>>(Q, K, M);
    topk_kernel<<<B_ * H_, 256, 0, stream>>>(M, mt);
    cumsum_kernel<<<B_ * H_ * 2, 1024, 0, stream>>>(V, out);
    attn_kernel<<<B_ * H_ * NTOP, 256, 0, stream>>>(Q, K, V, mt, out);
  } else {
    cumsum_kernel<<<B_ * H_ * 2, 1024, 0, stream>>>(V, out);
    fused_kernel<<<B_ * H_, 256, 0, stream>>>(Q, K, V, out);
  }
}